// Round 8
// baseline (87.699 us; speedup 1.0000x reference)
//
#include <hip/hip_runtime.h>

// ElementalGTOLogNormalSkinCutoff on MI355X (gfx950) — round 8
//
// Round-5 structure (best: APB=16, 320 thr, 1024 blocks, thread=(atom,g),
// species-sorted fp32 LDS records, Horner-in-exp2 radial) with the phase-2
// loops de-overheaded:
//  * Each species segment PADDED to a multiple of 4 with exact-zero records
//    (c0=c1=0, c2=-200 -> exp2(-200) flushes to 0): no remainder code.
//  * x4 unroll, all 8 ds_reads issued before the 4 bodies — one lgkmcnt
//    stall per 4 records instead of per 1-2 (R6/R7 falsified the
//    LDS-issue-bound model; the slack is loop overhead + load latency).
//  * LDS rows padded to 81 slots (324 floats = 4 mod 32 banks: keeps the
//    per-atom bank stagger; 80 would alias all atoms onto the same banks).

#define B_   128
#define N_   128
#define M_   64
#define NG_  20
#define NSP_ 4
#define FPSIZE_ 600
#define APB  16                     // atoms per block (divides N_, so b uniform)
#define NTASK (APB * M_)            // 1024 neighbour slots per block
#define BLOCK_THREADS (APB * NG_)   // 320 = 5 waves
#define SLOTS 81                    // 64 + up to 12 pad + bank stagger

__global__ __launch_bounds__(BLOCK_THREADS)
void gto_fp_kernel(const float* __restrict__ coords,   // [B,N,3]
                   const int*   __restrict__ charges,  // [B,N]
                   const int*   __restrict__ counts,   // [B]
                   const int*   __restrict__ neigh,    // [B,N,M]
                   float*       __restrict__ out)      // [B,N,600]
{
    __shared__ float4 sP[APB][SLOTS];       // c0, c1, c2, ux
    __shared__ float2 sQ[APB][SLOTS];       // uy, uz
    __shared__ int s_cnt[APB][NSP_];        // real counts
    __shared__ int s_pc[APB][NSP_];         // padded counts (multiple of 4)
    __shared__ int s_start[APB][NSP_];      // segment starts (padded prefix)
    __shared__ int s_pos[APB][NSP_];        // placement cursor

    const int tid = threadIdx.x;
    const int blockBase = blockIdx.x * APB;
    const int bidx = blockBase / N_;        // uniform: APB divides N_

    if (tid < APB * NSP_) ((int*)s_cnt)[tid] = 0;
    __syncthreads();

    // -------- phase 1a: count species per atom ---------------------------
    for (int t = tid; t < NTASK; t += BLOCK_THREADS) {
        const int la = t >> 6, m = t & 63;
        const int nb = neigh[(blockBase + la) * M_ + m];
        if (nb >= 0) {
            const int z = charges[bidx * N_ + nb];
            const int s = (z == 1) ? 0 : (z - 5);   // {1,6,7,8} -> {0,1,2,3}
            atomicAdd(&s_cnt[la][s], 1);
        }
    }
    __syncthreads();

    // -------- prefix over padded counts ----------------------------------
    if (tid < APB) {
        int st = 0;
#pragma unroll
        for (int s = 0; s < NSP_; ++s) {
            const int c  = s_cnt[tid][s];
            const int pc = (c + 3) & ~3;
            s_pc[tid][s]    = pc;
            s_start[tid][s] = st;
            s_pos[tid][s]   = st;
            st += pc;
        }
    }
    __syncthreads();

    // -------- phase 1b: build records straight into sorted slots ---------
    for (int t = tid; t < NTASK; t += BLOCK_THREADS) {
        const int la = t >> 6, m = t & 63;
        const int atom = blockBase + la;
        const int nb = neigh[atom * M_ + m];
        if (nb < 0) continue;
        const int nidx = bidx * N_ + nb;
        const float dx = coords[atom * 3 + 0] - coords[nidx * 3 + 0];
        const float dy = coords[atom * 3 + 1] - coords[nidx * 3 + 1];
        const float dz = coords[atom * 3 + 2] - coords[nidx * 3 + 2];
        const int   z  = charges[nidx];

        const float d2     = dx * dx + dy * dy + dz * dz;
        const float inv_d  = __builtin_amdgcn_rsqf(d2);
        const float d      = d2 * inv_d;
        const float inv_d2 = inv_d * inv_d;

        const float dsw  = (d - 1.0f) * 0.2f;
        const float dsw2 = dsw * dsw;
        const float cut  = 1.0f - dsw2 * dsw * fmaf(6.0f, dsw2, fmaf(-15.0f, dsw, 10.0f));

        const float sigma2 = __logf(fmaf(2.0f, inv_d2, 1.0f));     // log(1+W/d^2)
        const float mu     = 0.5f * (__logf(d2) - sigma2);         // log(d)-s2/2
        const float amp    = fmaxf(__builtin_amdgcn_rsqf(sigma2) * cut * inv_d2,
                                   1.0e-30f);   // cut can be ~-1e-7 at d~6

        const float F   = -0.72134752f * __builtin_amdgcn_rcpf(sigma2); // -0.5*log2e/s2
        const float Fm  = F * mu;
        const float c2v = fmaf(Fm, mu, __log2f(amp));

        const int s = (z == 1) ? 0 : (z - 5);
        const int slot = atomicAdd(&s_pos[la][s], 1);
        sP[la][slot] = make_float4(F, -(Fm + Fm), c2v, dx * inv_d);
        sQ[la][slot] = make_float2(dy * inv_d, dz * inv_d);
    }

    // -------- pad fill: zero-contribution records ------------------------
    if (tid < APB * NSP_) {
        const int la = tid >> 2, s = tid & 3;
        const int st = s_start[la][s];
        const int c  = s_cnt[la][s];
        const int pc = s_pc[la][s];
        for (int k = st + c; k < st + pc; ++k) {
            sP[la][k] = make_float4(0.0f, 0.0f, -200.0f, 0.0f);  // rad = 2^-200 = 0
            sQ[la][k] = make_float2(0.0f, 0.0f);
        }
    }
    __syncthreads();

    // -------- phase 2: thread = (atom, g); accumulate T[4][10] -----------
    const int g  = tid % NG_;
    const int la = tid / NG_;
    const int atom = blockBase + la;
    const int n = atom % N_;

    const float off = 0.3f * (float)(g + 1);
    const float lo  = __logf(off);
    const float lo2 = lo * lo;
    const float inv_off_spi = 1.0f / (off * 1.7724538509055159f);

    float T[NSP_][10];
#pragma unroll
    for (int s = 0; s < NSP_; ++s)
#pragma unroll
        for (int a = 0; a < 10; ++a) T[s][a] = 0.0f;

#define BODY(SS, P, Q)                                                        \
    {                                                                         \
        const float rad = __builtin_amdgcn_exp2f(                             \
            fmaf(P.x, lo2, fmaf(P.y, lo, P.z)));                              \
        const float rx = rad * P.w, ry = rad * Q.x, rz = rad * Q.y;           \
        T[SS][0] += rad;                                                      \
        T[SS][1] += rx;  T[SS][2] += ry;  T[SS][3] += rz;                     \
        T[SS][4] = fmaf(rx, P.w, T[SS][4]);                                   \
        T[SS][5] = fmaf(rx, Q.x, T[SS][5]);                                   \
        T[SS][6] = fmaf(ry, Q.x, T[SS][6]);                                   \
        T[SS][7] = fmaf(rx, Q.y, T[SS][7]);                                   \
        T[SS][8] = fmaf(ry, Q.y, T[SS][8]);                                   \
        T[SS][9] = fmaf(rz, Q.y, T[SS][9]);                                   \
    }

#define ACC(SS)                                                               \
    {                                                                         \
        const int e0 = s_start[la][SS];                                       \
        const int e1 = e0 + s_pc[la][SS];   /* multiple of 4: no remainder */ \
        for (int m = e0; m < e1; m += 4) {                                    \
            const float4 Pa = sP[la][m + 0]; const float2 Qa = sQ[la][m + 0]; \
            const float4 Pb = sP[la][m + 1]; const float2 Qb = sQ[la][m + 1]; \
            const float4 Pc = sP[la][m + 2]; const float2 Qc = sQ[la][m + 2]; \
            const float4 Pd = sP[la][m + 3]; const float2 Qd = sQ[la][m + 3]; \
            BODY(SS, Pa, Qa)                                                  \
            BODY(SS, Pb, Qb)                                                  \
            BODY(SS, Pc, Qc)                                                  \
            BODY(SS, Pd, Qd)                                                  \
        }                                                                     \
    }
    ACC(0) ACC(1) ACC(2) ACC(3)
#undef ACC
#undef BODY

    // -------- epilogue: 30 outputs for this g ----------------------------
    const float amask = (n < counts[bidx]) ? 1.0f : 0.0f;
    const float scale = amask * inv_off_spi * inv_off_spi;
    float* op = out + atom * FPSIZE_ + g;

    // angw = [1, 1,1,1, 1,2,1,2,2,1]; lw = 1 for all l
#pragma unroll
    for (int l = 0; l < 3; ++l) {
        const int a0 = (l == 0) ? 0 : (l == 1) ? 1 : 4;
        const int a1 = (l == 0) ? 1 : (l == 1) ? 4 : 10;
#pragma unroll
        for (int s = 0; s < NSP_; ++s) {
            float v = 0.0f;
#pragma unroll
            for (int a = a0; a < a1; ++a) {
                const float w = (a == 5 || a == 7 || a == 8) ? 2.0f : 1.0f;
                v = fmaf(w * T[s][a], T[s][a], v);
            }
            op[(l * 10 + s) * NG_] = scale * v;
        }
        int mb = 4;
#pragma unroll
        for (int i = 0; i < NSP_; ++i) {
#pragma unroll
            for (int j = i + 1; j < NSP_; ++j) {
                float v = 0.0f;
#pragma unroll
                for (int a = a0; a < a1; ++a) {
                    const float w = (a == 5 || a == 7 || a == 8) ? 2.0f : 1.0f;
                    v = fmaf(w * T[i][a], T[j][a], v);
                }
                op[(l * 10 + mb) * NG_] = scale * (2.0f * v);
                ++mb;
            }
        }
    }
}

extern "C" void kernel_launch(void* const* d_in, const int* in_sizes, int n_in,
                              void* d_out, int out_size, void* d_ws, size_t ws_size,
                              hipStream_t stream) {
    const float* coords  = (const float*)d_in[0];
    const int*   charges = (const int*)d_in[1];
    const int*   counts  = (const int*)d_in[2];
    const int*   neigh   = (const int*)d_in[3];
    float*       outp    = (float*)d_out;

    const int blocks = (B_ * N_) / APB;   // 1024
    gto_fp_kernel<<<blocks, BLOCK_THREADS, 0, stream>>>(coords, charges, counts, neigh, outp);
}

// Round 9
// 85.078 us; speedup vs baseline: 1.0308x; 1.0308x over previous
//
#include <hip/hip_runtime.h>

// ElementalGTOLogNormalSkinCutoff on MI355X (gfx950) — round 9
//
// Phase 1 rebuilt wave-synchronous: one WAVE per atom, lane = neighbour slot
// (M=64 = wave width -> neigh row load is one coalesced dword per lane).
// Species bucket-sort via 4 ballots + popcount prefix — no LDS atomics, no
// separate count pass, ONE barrier total (was 4). Phase 2 is round-5's
// best-measured form: fp32 24B records, Horner-in-exp2 radial, x2 unroll.
//
// Rationale: rounds 6-8 (three different phase-2 variants) all landed within
// noise (84-88 us) — phase 2 LDS reads are same-address broadcasts across the
// 20 g-lanes of an atom, so phase 2 was never LDS-bound. The remaining slack
// is phase-1 passes/atomics and barrier drains, attacked here.

#define B_   128
#define N_   128
#define M_   64
#define NG_  20
#define NSP_ 4
#define FPSIZE_ 600
#define APB  16                     // atoms per block (divides N_, so b uniform)
#define BLOCK_THREADS (APB * NG_)   // 320 = 5 waves
#define NWAVES 5

__global__ __launch_bounds__(BLOCK_THREADS)
void gto_fp_kernel(const float* __restrict__ coords,   // [B,N,3]
                   const int*   __restrict__ charges,  // [B,N]
                   const int*   __restrict__ counts,   // [B]
                   const int*   __restrict__ neigh,    // [B,N,M]
                   float*       __restrict__ out)      // [B,N,600]
{
    __shared__ float4 sP[APB][M_ + 1];      // c0, c1, c2, ux  (padded row)
    __shared__ float2 sQ[APB][M_ + 1];      // uy, uz          (padded row)
    __shared__ int s_cnt[APB][NSP_];
    __shared__ int s_start[APB][NSP_];

    const int tid  = threadIdx.x;
    const int wave = tid >> 6;
    const int lane = tid & 63;
    const int blockBase = blockIdx.x * APB;
    const int bidx = blockBase / N_;        // uniform: APB divides N_

    // -------- phase 1: one wave per atom, lane = neighbour slot ----------
    for (int la = wave; la < APB; la += NWAVES) {
        const int atom = blockBase + la;
        const int nb = neigh[atom * M_ + lane];     // coalesced: 64 lanes, 256B
        const bool valid = (nb >= 0);
        const int nidx = bidx * N_ + (valid ? nb : 0);

        const float dx = coords[atom * 3 + 0] - coords[nidx * 3 + 0];
        const float dy = coords[atom * 3 + 1] - coords[nidx * 3 + 1];
        const float dz = coords[atom * 3 + 2] - coords[nidx * 3 + 2];
        const int   z  = charges[nidx];

        const float d2     = dx * dx + dy * dy + dz * dz;
        const float inv_d  = __builtin_amdgcn_rsqf(d2);
        const float d      = d2 * inv_d;
        const float inv_d2 = inv_d * inv_d;

        const float dsw  = (d - 1.0f) * 0.2f;
        const float dsw2 = dsw * dsw;
        const float cut  = 1.0f - dsw2 * dsw * fmaf(6.0f, dsw2, fmaf(-15.0f, dsw, 10.0f));

        const float sigma2 = __logf(fmaf(2.0f, inv_d2, 1.0f));     // log(1+W/d^2)
        const float mu     = 0.5f * (__logf(d2) - sigma2);         // log(d)-s2/2
        const float amp    = fmaxf(__builtin_amdgcn_rsqf(sigma2) * cut * inv_d2,
                                   1.0e-30f);   // cut can be ~-1e-7 at d~6

        const float F   = -0.72134752f * __builtin_amdgcn_rcpf(sigma2); // -0.5*log2e/s2
        const float Fm  = F * mu;
        const float c2v = fmaf(Fm, mu, __log2f(amp));

        const int s = (z == 1) ? 0 : (z - 5);   // {1,6,7,8} -> {0,1,2,3}

        // ballot-based bucket sort: counts, starts, and this lane's slot
        const unsigned long long m0 = __ballot(valid && s == 0);
        const unsigned long long m1 = __ballot(valid && s == 1);
        const unsigned long long m2 = __ballot(valid && s == 2);
        const unsigned long long m3 = __ballot(valid && s == 3);
        const int c0 = __popcll(m0), c1 = __popcll(m1), c2 = __popcll(m2);
        const unsigned long long below = (lane == 63) ? ~0ULL >> 1
                                                      : (1ULL << lane) - 1ULL;
        if (valid) {
            int slot;
            if      (s == 0) slot = __popcll(m0 & below);
            else if (s == 1) slot = c0 + __popcll(m1 & below);
            else if (s == 2) slot = c0 + c1 + __popcll(m2 & below);
            else             slot = c0 + c1 + c2 + __popcll(m3 & below);
            sP[la][slot] = make_float4(F, -(Fm + Fm), c2v, dx * inv_d);
            sQ[la][slot] = make_float2(dy * inv_d, dz * inv_d);
        }
        if (lane == 0) {
            s_cnt[la][0] = c0; s_cnt[la][1] = c1;
            s_cnt[la][2] = c2; s_cnt[la][3] = __popcll(m3);
            s_start[la][0] = 0;
            s_start[la][1] = c0;
            s_start[la][2] = c0 + c1;
            s_start[la][3] = c0 + c1 + c2;
        }
    }
    __syncthreads();                            // the ONLY barrier

    // -------- phase 2: thread = (atom, g); accumulate T[4][10] -----------
    const int g  = tid % NG_;
    const int la = tid / NG_;
    const int atom = blockBase + la;
    const int n = atom % N_;

    const float off = 0.3f * (float)(g + 1);
    const float lo  = __logf(off);
    const float lo2 = lo * lo;
    const float inv_off_spi = 1.0f / (off * 1.7724538509055159f);

    float T[NSP_][10];
#pragma unroll
    for (int s = 0; s < NSP_; ++s)
#pragma unroll
        for (int a = 0; a < 10; ++a) T[s][a] = 0.0f;

#define BODY(SS, P, Q)                                                        \
    {                                                                         \
        const float rad = __builtin_amdgcn_exp2f(                             \
            fmaf(P.x, lo2, fmaf(P.y, lo, P.z)));                              \
        const float rx = rad * P.w, ry = rad * Q.x, rz = rad * Q.y;           \
        T[SS][0] += rad;                                                      \
        T[SS][1] += rx;  T[SS][2] += ry;  T[SS][3] += rz;                     \
        T[SS][4] = fmaf(rx, P.w, T[SS][4]);                                   \
        T[SS][5] = fmaf(rx, Q.x, T[SS][5]);                                   \
        T[SS][6] = fmaf(ry, Q.x, T[SS][6]);                                   \
        T[SS][7] = fmaf(rx, Q.y, T[SS][7]);                                   \
        T[SS][8] = fmaf(ry, Q.y, T[SS][8]);                                   \
        T[SS][9] = fmaf(rz, Q.y, T[SS][9]);                                   \
    }

#define ACC(SS)                                                               \
    {                                                                         \
        const int e0 = s_start[la][SS];                                       \
        const int e1 = e0 + s_cnt[la][SS];                                    \
        int m = e0;                                                           \
        for (; m + 1 < e1; m += 2) {                                          \
            const float4 Pa = sP[la][m];     const float2 Qa = sQ[la][m];     \
            const float4 Pb = sP[la][m + 1]; const float2 Qb = sQ[la][m + 1]; \
            BODY(SS, Pa, Qa)                                                  \
            BODY(SS, Pb, Qb)                                                  \
        }                                                                     \
        if (m < e1) {                                                         \
            const float4 Pa = sP[la][m]; const float2 Qa = sQ[la][m];         \
            BODY(SS, Pa, Qa)                                                  \
        }                                                                     \
    }
    ACC(0) ACC(1) ACC(2) ACC(3)
#undef ACC
#undef BODY

    // -------- epilogue: 30 outputs for this g ----------------------------
    const float amask = (n < counts[bidx]) ? 1.0f : 0.0f;
    const float scale = amask * inv_off_spi * inv_off_spi;
    float* op = out + atom * FPSIZE_ + g;

    // angw = [1, 1,1,1, 1,2,1,2,2,1]; lw = 1 for all l
#pragma unroll
    for (int l = 0; l < 3; ++l) {
        const int a0 = (l == 0) ? 0 : (l == 1) ? 1 : 4;
        const int a1 = (l == 0) ? 1 : (l == 1) ? 4 : 10;
#pragma unroll
        for (int s = 0; s < NSP_; ++s) {
            float v = 0.0f;
#pragma unroll
            for (int a = a0; a < a1; ++a) {
                const float w = (a == 5 || a == 7 || a == 8) ? 2.0f : 1.0f;
                v = fmaf(w * T[s][a], T[s][a], v);
            }
            op[(l * 10 + s) * NG_] = scale * v;
        }
        int mb = 4;
#pragma unroll
        for (int i = 0; i < NSP_; ++i) {
#pragma unroll
            for (int j = i + 1; j < NSP_; ++j) {
                float v = 0.0f;
#pragma unroll
                for (int a = a0; a < a1; ++a) {
                    const float w = (a == 5 || a == 7 || a == 8) ? 2.0f : 1.0f;
                    v = fmaf(w * T[i][a], T[j][a], v);
                }
                op[(l * 10 + mb) * NG_] = scale * (2.0f * v);
                ++mb;
            }
        }
    }
}

extern "C" void kernel_launch(void* const* d_in, const int* in_sizes, int n_in,
                              void* d_out, int out_size, void* d_ws, size_t ws_size,
                              hipStream_t stream) {
    const float* coords  = (const float*)d_in[0];
    const int*   charges = (const int*)d_in[1];
    const int*   counts  = (const int*)d_in[2];
    const int*   neigh   = (const int*)d_in[3];
    float*       outp    = (float*)d_out;

    const int blocks = (B_ * N_) / APB;   // 1024
    gto_fp_kernel<<<blocks, BLOCK_THREADS, 0, stream>>>(coords, charges, counts, neigh, outp);
}